// Round 1
// baseline (718.645 us; speedup 1.0000x reference)
//
#include <hip/hip_runtime.h>
#include <math.h>

// Sizes: b=4, t=12 (BT=48), n=512, c=64, heads=8, hd=8, FF hidden=256, depth=2
#define LDSP 68   // padded LDS row stride in floats (17 float4s -> odd quad stride, conflict-free)

// ---------------- init: h[(bt*512+v)*64+c] = x[b,c,v,t] + pos[v,c] ----------------
__global__ __launch_bounds__(256) void k_init(const float* __restrict__ x,
                                              const float* __restrict__ pos,
                                              float* __restrict__ h) {
    int i = blockIdx.x * 256 + threadIdx.x;          // over 1572864 h elements
    int c = i & 63;
    int v = (i >> 6) & 511;
    int bt = i >> 15;
    int b = bt / 12, t = bt - b * 12;
    h[i] = x[(((size_t)(b * 64 + c) * 512) + v) * 12 + t] + pos[v * 64 + c];
}

// ---------------- transpose h -> rbuf[(v*48+bt)*64+c]  (residual snapshot) ----------------
__global__ __launch_bounds__(256) void k_trans(const float* __restrict__ h,
                                               float* __restrict__ rb) {
    int f = blockIdx.x * 256 + threadIdx.x;          // float4 idx over 393216
    int c4 = f & 15;
    int row = f >> 4;                                 // v*48+bt
    int v = row / 48, bt = row - v * 48;
    ((float4*)rb)[f] = ((const float4*)h)[((size_t)(bt * 512 + v)) * 16 + c4];
}

// ---------------- qkv GEMM: [24576,64] @ [192,64]^T, scatter to q/k/v [bt,head,v,d] ----------------
__global__ __launch_bounds__(256) void k_qkv(const float* __restrict__ A,
                                             const float* __restrict__ W,
                                             float* __restrict__ qb,
                                             float* __restrict__ kb,
                                             float* __restrict__ vb) {
    __shared__ float a_lds[64 * LDSP];
    __shared__ float w_lds[64 * LDSP];
    int tid = threadIdx.x;
    int row0 = blockIdx.x * 64;
    int s = blockIdx.y;                               // 0=q 1=k 2=v
    int wave = tid >> 6, lane = tid & 63;
    int tr = (lane >> 3) + ((wave >> 1) << 3);        // 0..15
    int tc = (lane & 7) + ((wave & 1) << 3);          // 0..15

#pragma unroll
    for (int i = 0; i < 4; ++i) {
        int f = tid + i * 256;
        int r = f >> 4, k4 = f & 15;
        *(float4*)&a_lds[r * LDSP + k4 * 4] = ((const float4*)A)[(size_t)(row0 + r) * 16 + k4];
        *(float4*)&w_lds[r * LDSP + k4 * 4] = ((const float4*)W)[(size_t)(s * 64 + r) * 16 + k4];
    }
    __syncthreads();

    float acc[4][4] = {};
#pragma unroll
    for (int k4 = 0; k4 < 16; ++k4) {
        float4 a4[4], w4[4];
#pragma unroll
        for (int i = 0; i < 4; ++i) a4[i] = *(const float4*)&a_lds[(tr + 16 * i) * LDSP + k4 * 4];
#pragma unroll
        for (int j = 0; j < 4; ++j) w4[j] = *(const float4*)&w_lds[(tc + 16 * j) * LDSP + k4 * 4];
#pragma unroll
        for (int i = 0; i < 4; ++i)
#pragma unroll
            for (int j = 0; j < 4; ++j)
                acc[i][j] += a4[i].x * w4[j].x + a4[i].y * w4[j].y + a4[i].z * w4[j].z + a4[i].w * w4[j].w;
    }

    float* dst = (s == 0) ? qb : ((s == 1) ? kb : vb);
#pragma unroll
    for (int i = 0; i < 4; ++i) {
        int row = row0 + tr + 16 * i;
        int bt = row >> 9, v = row & 511;
#pragma unroll
        for (int j = 0; j < 4; ++j) {
            int o = tc + 16 * j;
            int head = o >> 3, d = o & 7;
            dst[(((size_t)(bt * 8 + head)) * 512 + v) * 8 + d] = acc[i][j];
        }
    }
}

// ---------------- attention: one block per (bt*8+head, half); online softmax ----------------
__global__ __launch_bounds__(256) void k_attn(const float* __restrict__ qb,
                                              const float* __restrict__ kb,
                                              const float* __restrict__ vb,
                                              float* __restrict__ ob) {
    __shared__ float kl[512 * 8];
    __shared__ float vl[512 * 8];
    int bh = blockIdx.x;
    int half = blockIdx.y;
    int tid = threadIdx.x;
    const float4* kp = (const float4*)(kb + (size_t)bh * 4096);
    const float4* vp = (const float4*)(vb + (size_t)bh * 4096);
#pragma unroll
    for (int i = 0; i < 4; ++i) {
        ((float4*)kl)[tid + i * 256] = kp[tid + i * 256];
        ((float4*)vl)[tid + i * 256] = vp[tid + i * 256];
    }
    __syncthreads();

    int row = half * 256 + tid;
    const float* qp = qb + (size_t)bh * 4096 + row * 8;
    float4 q0 = *(const float4*)qp;
    float4 q1 = *(const float4*)(qp + 4);
    const float scale = 0.35355339059327373f;  // 8^-0.5
    float m = -1e30f, lsum = 0.f;
    float acc[8] = {};
    for (int j = 0; j < 512; ++j) {
        float4 k0 = *(const float4*)&kl[j * 8];
        float4 k1 = *(const float4*)&kl[j * 8 + 4];
        float s = q0.x * k0.x + q0.y * k0.y + q0.z * k0.z + q0.w * k0.w
                + q1.x * k1.x + q1.y * k1.y + q1.z * k1.z + q1.w * k1.w;
        s *= scale;
        float mn = fmaxf(m, s);
        float corr = __expf(m - mn);
        float p = __expf(s - mn);
        lsum = lsum * corr + p;
        float4 v0 = *(const float4*)&vl[j * 8];
        float4 v1 = *(const float4*)&vl[j * 8 + 4];
        acc[0] = acc[0] * corr + p * v0.x;
        acc[1] = acc[1] * corr + p * v0.y;
        acc[2] = acc[2] * corr + p * v0.z;
        acc[3] = acc[3] * corr + p * v0.w;
        acc[4] = acc[4] * corr + p * v1.x;
        acc[5] = acc[5] * corr + p * v1.y;
        acc[6] = acc[6] * corr + p * v1.z;
        acc[7] = acc[7] * corr + p * v1.w;
        m = mn;
    }
    float inv = 1.f / lsum;
    int bt = bh >> 3, head = bh & 7;
    float* op = ob + ((size_t)(bt * 512 + row)) * 64 + head * 8;
    *(float4*)op = make_float4(acc[0] * inv, acc[1] * inv, acc[2] * inv, acc[3] * inv);
    *(float4*)(op + 4) = make_float4(acc[4] * inv, acc[5] * inv, acc[6] * inv, acc[7] * inv);
}

// ---------------- proj GEMM + bias + residual add into h ----------------
__global__ __launch_bounds__(256) void k_proj(const float* __restrict__ A,
                                              const float* __restrict__ W,
                                              const float* __restrict__ bias,
                                              float* __restrict__ h) {
    __shared__ float a_lds[64 * LDSP];
    __shared__ float w_lds[64 * LDSP];
    int tid = threadIdx.x;
    int row0 = blockIdx.x * 64;
    int wave = tid >> 6, lane = tid & 63;
    int tr = (lane >> 3) + ((wave >> 1) << 3);
    int tc = (lane & 7) + ((wave & 1) << 3);
#pragma unroll
    for (int i = 0; i < 4; ++i) {
        int f = tid + i * 256;
        int r = f >> 4, k4 = f & 15;
        *(float4*)&a_lds[r * LDSP + k4 * 4] = ((const float4*)A)[(size_t)(row0 + r) * 16 + k4];
        *(float4*)&w_lds[r * LDSP + k4 * 4] = ((const float4*)W)[(size_t)r * 16 + k4];
    }
    __syncthreads();
    float acc[4][4] = {};
#pragma unroll
    for (int k4 = 0; k4 < 16; ++k4) {
        float4 a4[4], w4[4];
#pragma unroll
        for (int i = 0; i < 4; ++i) a4[i] = *(const float4*)&a_lds[(tr + 16 * i) * LDSP + k4 * 4];
#pragma unroll
        for (int j = 0; j < 4; ++j) w4[j] = *(const float4*)&w_lds[(tc + 16 * j) * LDSP + k4 * 4];
#pragma unroll
        for (int i = 0; i < 4; ++i)
#pragma unroll
            for (int j = 0; j < 4; ++j)
                acc[i][j] += a4[i].x * w4[j].x + a4[i].y * w4[j].y + a4[i].z * w4[j].z + a4[i].w * w4[j].w;
    }
#pragma unroll
    for (int i = 0; i < 4; ++i) {
        int row = row0 + tr + 16 * i;
#pragma unroll
        for (int j = 0; j < 4; ++j) {
            int o = tc + 16 * j;
            h[(size_t)row * 64 + o] += acc[i][j] + bias[o];
        }
    }
}

// ---------------- layernorm (wave per token) -> xhat ----------------
__global__ __launch_bounds__(256) void k_ln(const float* __restrict__ h,
                                            const float* __restrict__ g,
                                            const float* __restrict__ bln,
                                            float* __restrict__ xhat) {
    int wave = threadIdx.x >> 6, lane = threadIdx.x & 63;
    int row = blockIdx.x * 4 + wave;
    float x = h[(size_t)row * 64 + lane];
    float s = x, s2 = x * x;
#pragma unroll
    for (int mk = 32; mk; mk >>= 1) {
        s += __shfl_xor(s, mk);
        s2 += __shfl_xor(s2, mk);
    }
    float mean = s * (1.f / 64.f);
    float var = s2 * (1.f / 64.f) - mean * mean;
    float r = rsqrtf(var + 1e-5f);
    xhat[(size_t)row * 64 + lane] = (x - mean) * r * g[lane] + bln[lane];
}

// ---------------- ff1 GEMM + bias + exact gelu -> yb [row,256] ----------------
__global__ __launch_bounds__(256) void k_ff1(const float* __restrict__ A,
                                             const float* __restrict__ W,
                                             const float* __restrict__ bias,
                                             float* __restrict__ yb) {
    __shared__ float a_lds[64 * LDSP];
    __shared__ float w_lds[64 * LDSP];
    int tid = threadIdx.x;
    int row0 = blockIdx.x * 64;
    int col0 = blockIdx.y * 64;
    int wave = tid >> 6, lane = tid & 63;
    int tr = (lane >> 3) + ((wave >> 1) << 3);
    int tc = (lane & 7) + ((wave & 1) << 3);
#pragma unroll
    for (int i = 0; i < 4; ++i) {
        int f = tid + i * 256;
        int r = f >> 4, k4 = f & 15;
        *(float4*)&a_lds[r * LDSP + k4 * 4] = ((const float4*)A)[(size_t)(row0 + r) * 16 + k4];
        *(float4*)&w_lds[r * LDSP + k4 * 4] = ((const float4*)W)[(size_t)(col0 + r) * 16 + k4];
    }
    __syncthreads();
    float acc[4][4] = {};
#pragma unroll
    for (int k4 = 0; k4 < 16; ++k4) {
        float4 a4[4], w4[4];
#pragma unroll
        for (int i = 0; i < 4; ++i) a4[i] = *(const float4*)&a_lds[(tr + 16 * i) * LDSP + k4 * 4];
#pragma unroll
        for (int j = 0; j < 4; ++j) w4[j] = *(const float4*)&w_lds[(tc + 16 * j) * LDSP + k4 * 4];
#pragma unroll
        for (int i = 0; i < 4; ++i)
#pragma unroll
            for (int j = 0; j < 4; ++j)
                acc[i][j] += a4[i].x * w4[j].x + a4[i].y * w4[j].y + a4[i].z * w4[j].z + a4[i].w * w4[j].w;
    }
#pragma unroll
    for (int i = 0; i < 4; ++i) {
        int row = row0 + tr + 16 * i;
#pragma unroll
        for (int j = 0; j < 4; ++j) {
            int o = col0 + tc + 16 * j;
            float xg = acc[i][j] + bias[o];
            yb[(size_t)row * 256 + o] = 0.5f * xg * (1.0f + erff(xg * 0.70710678118654752f));
        }
    }
}

// ---------------- ff2 GEMM (K=256) + bias + residual add into h ----------------
__global__ __launch_bounds__(256) void k_ff2(const float* __restrict__ A,
                                             const float* __restrict__ W,
                                             const float* __restrict__ bias,
                                             float* __restrict__ h) {
    __shared__ float a_lds[64 * LDSP];
    __shared__ float w_lds[64 * LDSP];
    int tid = threadIdx.x;
    int row0 = blockIdx.x * 64;
    int wave = tid >> 6, lane = tid & 63;
    int tr = (lane >> 3) + ((wave >> 1) << 3);
    int tc = (lane & 7) + ((wave & 1) << 3);
    float acc[4][4] = {};
    for (int kc = 0; kc < 4; ++kc) {
#pragma unroll
        for (int i = 0; i < 4; ++i) {
            int f = tid + i * 256;
            int r = f >> 4, k4 = f & 15;
            *(float4*)&a_lds[r * LDSP + k4 * 4] = ((const float4*)A)[(size_t)(row0 + r) * 64 + kc * 16 + k4];
            *(float4*)&w_lds[r * LDSP + k4 * 4] = ((const float4*)W)[(size_t)r * 64 + kc * 16 + k4];
        }
        __syncthreads();
#pragma unroll
        for (int k4 = 0; k4 < 16; ++k4) {
            float4 a4[4], w4[4];
#pragma unroll
            for (int i = 0; i < 4; ++i) a4[i] = *(const float4*)&a_lds[(tr + 16 * i) * LDSP + k4 * 4];
#pragma unroll
            for (int j = 0; j < 4; ++j) w4[j] = *(const float4*)&w_lds[(tc + 16 * j) * LDSP + k4 * 4];
#pragma unroll
            for (int i = 0; i < 4; ++i)
#pragma unroll
                for (int j = 0; j < 4; ++j)
                    acc[i][j] += a4[i].x * w4[j].x + a4[i].y * w4[j].y + a4[i].z * w4[j].z + a4[i].w * w4[j].w;
        }
        __syncthreads();
    }
#pragma unroll
    for (int i = 0; i < 4; ++i) {
        int row = row0 + tr + 16 * i;
#pragma unroll
        for (int j = 0; j < 4; ++j) {
            int o = tc + 16 * j;
            h[(size_t)row * 64 + o] += acc[i][j] + bias[o];
        }
    }
}

// ---------------- diffusion: out[w,j] = sum_v adj[v,w]*in[v,j]  (outer-product form) ----------------
__global__ __launch_bounds__(256) void k_diff(const float* __restrict__ adj,
                                              const float* __restrict__ in,
                                              float* __restrict__ outb) {
    __shared__ float a_lds[64 * LDSP];
    __shared__ float b_lds[64 * LDSP];
    int tid = threadIdx.x;
    int w0 = blockIdx.x * 64;    // 8 tiles over w
    int wave = tid >> 6, lane = tid & 63;
    int tw = (lane >> 3) + ((wave >> 1) << 3);   // 0..15
    int tj = (lane & 7) + ((wave & 1) << 3);     // 0..15
    float acc[4][4] = {};
    for (int kc = 0; kc < 8; ++kc) {
#pragma unroll
        for (int i = 0; i < 4; ++i) {
            int f = tid + i * 256;
            int r = f >> 4, q = f & 15;          // r = local v
            *(float4*)&a_lds[r * LDSP + q * 4] = ((const float4*)adj)[(size_t)(kc * 64 + r) * 128 + blockIdx.x * 16 + q];
            *(float4*)&b_lds[r * LDSP + q * 4] = ((const float4*)in)[(size_t)(kc * 64 + r) * 768 + blockIdx.y * 16 + q];
        }
        __syncthreads();
#pragma unroll 8
        for (int vv = 0; vv < 64; ++vv) {
            float4 a4 = *(const float4*)&a_lds[vv * LDSP + tw * 4];
            float4 b4 = *(const float4*)&b_lds[vv * LDSP + tj * 4];
            float av[4] = {a4.x, a4.y, a4.z, a4.w};
            float bv[4] = {b4.x, b4.y, b4.z, b4.w};
#pragma unroll
            for (int i = 0; i < 4; ++i)
#pragma unroll
                for (int j = 0; j < 4; ++j)
                    acc[i][j] += av[i] * bv[j];
        }
        __syncthreads();
    }
#pragma unroll
    for (int i = 0; i < 4; ++i) {
        ((float4*)outb)[(size_t)(w0 + tw * 4 + i) * 768 + blockIdx.y * 16 + tj] =
            make_float4(acc[i][0], acc[i][1], acc[i][2], acc[i][3]);
    }
}

// ---------------- gcn 1x1 conv over concat(r,x1,x2) + bias, add into h ----------------
__global__ __launch_bounds__(256) void k_gcn(const float* __restrict__ rb,
                                             const float* __restrict__ x1b,
                                             const float* __restrict__ x2b,
                                             const float* __restrict__ W,
                                             const float* __restrict__ bias,
                                             float* __restrict__ h) {
    __shared__ float a_lds[64 * LDSP];
    __shared__ float w_lds[64 * LDSP];
    int tid = threadIdx.x;
    int row0 = blockIdx.x * 64;                  // row = v*48 + bt
    int wave = tid >> 6, lane = tid & 63;
    int tr = (lane >> 3) + ((wave >> 1) << 3);
    int tc = (lane & 7) + ((wave & 1) << 3);
    const float* bases[3] = {rb, x1b, x2b};
    float acc[4][4] = {};
    for (int ch = 0; ch < 3; ++ch) {
        const float* A = bases[ch];
#pragma unroll
        for (int i = 0; i < 4; ++i) {
            int f = tid + i * 256;
            int r = f >> 4, k4 = f & 15;
            *(float4*)&a_lds[r * LDSP + k4 * 4] = ((const float4*)A)[(size_t)(row0 + r) * 16 + k4];
            *(float4*)&w_lds[r * LDSP + k4 * 4] = ((const float4*)W)[(size_t)r * 48 + ch * 16 + k4];
        }
        __syncthreads();
#pragma unroll
        for (int k4 = 0; k4 < 16; ++k4) {
            float4 a4[4], w4[4];
#pragma unroll
            for (int i = 0; i < 4; ++i) a4[i] = *(const float4*)&a_lds[(tr + 16 * i) * LDSP + k4 * 4];
#pragma unroll
            for (int j = 0; j < 4; ++j) w4[j] = *(const float4*)&w_lds[(tc + 16 * j) * LDSP + k4 * 4];
#pragma unroll
            for (int i = 0; i < 4; ++i)
#pragma unroll
                for (int j = 0; j < 4; ++j)
                    acc[i][j] += a4[i].x * w4[j].x + a4[i].y * w4[j].y + a4[i].z * w4[j].z + a4[i].w * w4[j].w;
        }
        __syncthreads();
    }
#pragma unroll
    for (int i = 0; i < 4; ++i) {
        int row = row0 + tr + 16 * i;
        int v = row / 48, bt = row - v * 48;
#pragma unroll
        for (int j = 0; j < 4; ++j) {
            int o = tc + 16 * j;
            h[((size_t)(bt * 512 + v)) * 64 + o] += acc[i][j] + bias[o];
        }
    }
}

// ---------------- final: out[b,c,v,t] = h[(b*12+t)*512+v][c] ----------------
__global__ __launch_bounds__(256) void k_out(const float* __restrict__ h,
                                             float* __restrict__ out) {
    int i = blockIdx.x * 256 + threadIdx.x;
    int t = i % 12;
    int r = i / 12;
    int v = r & 511;
    int r2 = r >> 9;
    int c = r2 & 63;
    int b = r2 >> 6;
    out[i] = h[(((size_t)(b * 12 + t) * 512) + v) * 64 + c];
}

extern "C" void kernel_launch(void* const* d_in, const int* in_sizes, int n_in,
                              void* d_out, int out_size, void* d_ws, size_t ws_size,
                              hipStream_t stream) {
    const float* x      = (const float*)d_in[0];
    const float* adj    = (const float*)d_in[1];
    const float* pos    = (const float*)d_in[2];
    const float* qkv_w  = (const float*)d_in[3];
    const float* proj_w = (const float*)d_in[4];
    const float* proj_b = (const float*)d_in[5];
    const float* ln_g   = (const float*)d_in[6];
    const float* ln_b   = (const float*)d_in[7];
    const float* ff_w1  = (const float*)d_in[8];
    const float* ff_b1  = (const float*)d_in[9];
    const float* ff_w2  = (const float*)d_in[10];
    const float* ff_b2  = (const float*)d_in[11];
    const float* gcn_w  = (const float*)d_in[12];
    const float* gcn_b  = (const float*)d_in[13];
    float* out = (float*)d_out;

    const size_t SZ = 1572864;  // 48*512*64
    float* h  = (float*)d_ws;
    float* rb = h  + SZ;
    float* x1 = rb + SZ;
    float* x2 = x1 + SZ;
    float* qb = x2 + SZ;
    float* kb = qb + SZ;
    float* vb = kb + SZ;
    float* ob = vb + SZ;
    float* yb = ob + SZ;       // 48*512*256
    float* xh = ob;            // ob is free after k_proj; reuse for LN output

    k_init<<<6144, 256, 0, stream>>>(x, pos, h);
    for (int l = 0; l < 2; ++l) {
        k_trans<<<1536, 256, 0, stream>>>(h, rb);
        k_qkv<<<dim3(384, 3), 256, 0, stream>>>(h, qkv_w + l * 12288, qb, kb, vb);
        k_attn<<<dim3(384, 2), 256, 0, stream>>>(qb, kb, vb, ob);
        k_proj<<<384, 256, 0, stream>>>(ob, proj_w + l * 4096, proj_b + l * 64, h);
        k_ln<<<6144, 256, 0, stream>>>(h, ln_g + l * 64, ln_b + l * 64, xh);
        k_ff1<<<dim3(384, 4), 256, 0, stream>>>(xh, ff_w1 + l * 16384, ff_b1 + l * 256, yb);
        k_ff2<<<384, 256, 0, stream>>>(yb, ff_w2 + l * 16384, ff_b2 + l * 64, h);
        k_diff<<<dim3(8, 48), 256, 0, stream>>>(adj, rb, x1);
        k_diff<<<dim3(8, 48), 256, 0, stream>>>(adj, x1, x2);
        k_gcn<<<384, 256, 0, stream>>>(rb, x1, x2, gcn_w + l * 12288, gcn_b + l * 64, h);
    }
    k_out<<<6144, 256, 0, stream>>>(h, out);
}